// Round 2
// baseline (746.586 us; speedup 1.0000x reference)
//
#include <hip/hip_runtime.h>

// ---------------------------------------------------------------------------
// VARS_D: fused linear-attention block on gfx950.
//
// Memory plan (round-2 fix: ws 419MB -> 117MB, all LDS <= 50.7KB):
//   qnT[bh][m][n] (100.7 MB) lives in d_out (exact size match; dead before K8).
//   qkv never materialized: K1 epilogue routes q->[bh][n][d], v->vT[bh][d][n].
//   Normalization folded: rn[m]rn[p] into K5 epilogue, rn[m] into sT (K6).
//
// Pipeline:
//  T   transpose weights -> bf16 (wqkvT, wprojT, rmT*8^-0.5)
//  K1  qkv GEMM: x(fp32,convert-on-load) @ WqkvT -> q[bh][n][d], vT[bh][d][n]
//  K2  halfnorm[bh][n] = ||q||^2 / 16
//  K3  rf GEMM: q @ rmT -> exp(.-hn)/sqrt(m); transposed write -> qnT (d_out);
//      colss[bh][m] += col sum-of-squares (atomics)
//  K5  kk|kv = qnT @ [qnT|vT]^T, K-split 8, rn-scaled, fp32 atomic accumulate
//  K6  ISTA solve -> sT[bh][d][m] * rn[m]
//  K7  attn = qnT^T @ sT^T (TN, LDS gather) -> attn[b][n][768] (aliases q)
//  K8  out = attn @ WprojT + bias (fp32, into d_out; qnT dead)
// ---------------------------------------------------------------------------

typedef __attribute__((ext_vector_type(8))) short bf16x8;   // 8 bf16 = 4 VGPRs
typedef __attribute__((ext_vector_type(4))) float f32x4;

__device__ __forceinline__ unsigned short f2bf(float f) {
  union { float f; unsigned int u; } v; v.f = f;
  unsigned int r = v.u + 0x7fffu + ((v.u >> 16) & 1u);   // RNE
  return (unsigned short)(r >> 16);
}
__device__ __forceinline__ float bf2f(unsigned short s) {
  union { unsigned int u; float f; } v; v.u = ((unsigned int)s) << 16;
  return v.f;
}
__device__ __forceinline__ float rn_of(float css) {  // 1/max(||col||,1e-12)
  return 1.f / fmaxf(sqrtf(css), 1e-12f);
}

// NT GEMM core: C[M,N] += A[M,K] * B^T[N,K], bf16, fp32 acc.
// 256 thr = 4 waves 2x2; mfma_f32_16x16x32_bf16:
//   A-frag m=lane&15,k=quad*8+j | B-frag n=lane&15 | C/D col=lane&15,row=quad*4+r
template<int BM, int BN>
__device__ __forceinline__ void gemm_core_nt(
    const unsigned short* __restrict__ A, int lda,
    const unsigned short* __restrict__ B0,
    const unsigned short* __restrict__ B1, int brows0, int ldb,
    int K,
    f32x4 (&acc)[BM / 32][BN / 32],
    unsigned short* As, unsigned short* Bs) {
  constexpr int MT = BM / 32, NT = BN / 32;
  const int tid = threadIdx.x;
  const int lane = tid & 63, wave = tid >> 6;
  const int wm = (wave >> 1) * (BM / 2), wn = (wave & 1) * (BN / 2);
  const int l16 = lane & 15, quad = lane >> 4;
#pragma unroll
  for (int i = 0; i < MT; i++)
#pragma unroll
    for (int j = 0; j < NT; j++)
#pragma unroll
      for (int r = 0; r < 4; r++) acc[i][j][r] = 0.f;

  for (int k0 = 0; k0 < K; k0 += 32) {
    __syncthreads();
#pragma unroll
    for (int c = 0; c < BM / 64; c++) {
      int chunk = tid + c * 256;
      int row = chunk >> 2, ko = (chunk & 3) << 3;
      *(uint4*)(As + row * 32 + ko) = *(const uint4*)(A + (long)row * lda + k0 + ko);
    }
#pragma unroll
    for (int c = 0; c < BN / 64; c++) {
      int chunk = tid + c * 256;
      int row = chunk >> 2, ko = (chunk & 3) << 3;
      const unsigned short* bp = (row < brows0) ? (B0 + (long)row * ldb)
                                                : (B1 + (long)(row - brows0) * ldb);
      *(uint4*)(Bs + row * 32 + ko) = *(const uint4*)(bp + k0 + ko);
    }
    __syncthreads();
    bf16x8 af[MT], bfr[NT];
#pragma unroll
    for (int i = 0; i < MT; i++)
      af[i] = *(const bf16x8*)(As + (wm + i * 16 + l16) * 32 + quad * 8);
#pragma unroll
    for (int j = 0; j < NT; j++)
      bfr[j] = *(const bf16x8*)(Bs + (wn + j * 16 + l16) * 32 + quad * 8);
#pragma unroll
    for (int i = 0; i < MT; i++)
#pragma unroll
      for (int j = 0; j < NT; j++)
        acc[i][j] = __builtin_amdgcn_mfma_f32_16x16x32_bf16(af[i], bfr[j], acc[i][j], 0, 0, 0);
  }
}

// ---------------- T: batched transpose fp32[R,C] -> bf16[C,R] ----------------
__global__ __launch_bounds__(256) void k_transpose_bf16(const float* __restrict__ in,
                                                        unsigned short* __restrict__ out,
                                                        int R, int C, float scale) {
  int b = blockIdx.y;
  long base = (long)b * R * C;
  long idx = (long)blockIdx.x * 256 + threadIdx.x;
  if (idx < (long)R * C) {
    int oc = (int)(idx / R);
    int orr = (int)(idx - (long)oc * R);
    out[base + idx] = f2bf(in[base + (long)orr * C + oc] * scale);
  }
}

// ---------------- K1: qkv GEMM, epilogue routes q / transposes v ----------------
__global__ __launch_bounds__(256) void k_gemm_qkv(const float* __restrict__ x,
                                                  const unsigned short* __restrict__ wqkvT,
                                                  unsigned short* __restrict__ q,
                                                  unsigned short* __restrict__ vT) {
  __shared__ __align__(16) unsigned short pool[8576];  // As|Bs staging, then T[64][134]
  unsigned short* As = pool;
  unsigned short* Bs = pool + 4096;
  f32x4 acc[4][4];
  const int ct = blockIdx.x, rt = blockIdx.y;
  const int tid = threadIdx.x, lane = tid & 63, wave = tid >> 6;
  const int l16 = lane & 15, quad = lane >> 4;
  const int wm = (wave >> 1) * 64, wn = (wave & 1) * 64;
#pragma unroll
  for (int i = 0; i < 4; i++)
#pragma unroll
    for (int j = 0; j < 4; j++)
#pragma unroll
      for (int r = 0; r < 4; r++) acc[i][j][r] = 0.f;

  const float* Ab = x + (long)rt * 128 * 768;
  const unsigned short* Bb = wqkvT + (long)ct * 128 * 768;
  for (int k0 = 0; k0 < 768; k0 += 32) {
    __syncthreads();
#pragma unroll
    for (int c = 0; c < 2; c++) {  // A: fp32 -> bf16 convert-on-load
      int chunk = tid + c * 256;
      int row = chunk >> 2, ko = (chunk & 3) << 3;
      const float* src = Ab + (long)row * 768 + k0 + ko;
      float4 f0 = *(const float4*)src;
      float4 f1 = *(const float4*)(src + 4);
      unsigned short o[8] = {f2bf(f0.x), f2bf(f0.y), f2bf(f0.z), f2bf(f0.w),
                             f2bf(f1.x), f2bf(f1.y), f2bf(f1.z), f2bf(f1.w)};
      *(uint4*)(As + row * 32 + ko) = *(uint4*)o;
    }
#pragma unroll
    for (int c = 0; c < 2; c++) {
      int chunk = tid + c * 256;
      int row = chunk >> 2, ko = (chunk & 3) << 3;
      *(uint4*)(Bs + row * 32 + ko) = *(const uint4*)(Bb + (long)row * 768 + k0 + ko);
    }
    __syncthreads();
    bf16x8 af[4], bfr[4];
#pragma unroll
    for (int i = 0; i < 4; i++)
      af[i] = *(const bf16x8*)(As + (wm + i * 16 + l16) * 32 + quad * 8);
#pragma unroll
    for (int j = 0; j < 4; j++)
      bfr[j] = *(const bf16x8*)(Bs + (wn + j * 16 + l16) * 32 + quad * 8);
#pragma unroll
    for (int i = 0; i < 4; i++)
#pragma unroll
      for (int j = 0; j < 4; j++)
        acc[i][j] = __builtin_amdgcn_mfma_f32_16x16x32_bf16(af[i], bfr[j], acc[i][j], 0, 0, 0);
  }

  const int b = rt >> 5;
  const int nbase = (rt & 31) * 128;
  if (ct < 6) {  // q columns: direct [bh][n][d] writes
#pragma unroll
    for (int i = 0; i < 4; i++)
#pragma unroll
      for (int j = 0; j < 4; j++)
#pragma unroll
        for (int r = 0; r < 4; r++) {
          int col = ct * 128 + wn + j * 16 + l16;
          int h = col >> 6, d = col & 63;
          int n = nbase + wm + i * 16 + quad * 4 + r;
          q[((long)(b * 12 + h) * 4096 + n) * 64 + d] = f2bf(acc[i][j][r]);
        }
  } else {  // v columns: two-pass LDS transpose -> vT[bh][d][n]
    for (int hh = 0; hh < 2; hh++) {
      __syncthreads();
      if ((wave >> 1) == hh) {
#pragma unroll
        for (int i = 0; i < 4; i++)
#pragma unroll
          for (int j = 0; j < 4; j++)
#pragma unroll
            for (int r = 0; r < 4; r++)
              pool[(i * 16 + quad * 4 + r) * 134 + wn + j * 16 + l16] = f2bf(acc[i][j][r]);
      }
      __syncthreads();
#pragma unroll
      for (int c = 0; c < 4; c++) {
        int chunk = tid + c * 256;
        int col = chunk >> 3, nj = (chunk & 7) * 8;
        unsigned short o[8];
#pragma unroll
        for (int e = 0; e < 8; e++) o[e] = pool[(nj + e) * 134 + col];
        int vcol = ct * 128 - 768 + col;
        int h = vcol >> 6, d = vcol & 63;
        long n = nbase + hh * 64 + nj;
        *(uint4*)&vT[((long)(b * 12 + h) * 64 + d) * 4096 + n] = *(uint4*)o;
      }
    }
  }
}

// ---------------- K2: halfnorm = ||q||^2 / 16 ----------------
__global__ __launch_bounds__(256) void k_halfnorm(const unsigned short* __restrict__ q,
                                                  float* __restrict__ hn) {
  int n = blockIdx.x * 256 + threadIdx.x;
  int bh = blockIdx.y;
  const uint4* p = (const uint4*)(q + ((long)bh * 4096 + n) * 64);
  float s = 0.f;
#pragma unroll
  for (int c = 0; c < 8; c++) {
    union { uint4 u; unsigned short s[8]; } u;
    u.u = p[c];
#pragma unroll
    for (int e = 0; e < 8; e++) { float f = bf2f(u.s[e]); s += f * f; }
  }
  hn[(long)bh * 4096 + n] = 0.0625f * s;  // 0.5 * scale(=1/8) * ||q||^2
}

// ---------------- K3: rf GEMM + transposed write to qnT + colss ----------------
__global__ __launch_bounds__(256) void k_gemm_rf(const unsigned short* __restrict__ q,
                                                 const unsigned short* __restrict__ rmT,
                                                 const float* __restrict__ halfnorm,
                                                 unsigned short* __restrict__ qnT,
                                                 float* __restrict__ colss) {
  __shared__ __align__(16) unsigned short pool[8576];
  __shared__ float css[128];
  f32x4 acc[4][4];
  const int nt = blockIdx.x, bh = blockIdx.y, h = bh % 12;
  const unsigned short* A = q + ((long)bh * 4096 + nt * 128) * 64;
  const unsigned short* B = rmT + (long)h * 8192;
  gemm_core_nt<128, 128>(A, 64, B, B, 128, 64, 64, acc, pool, pool + 4096);

  const int tid = threadIdx.x, lane = tid & 63, wave = tid >> 6;
  const int l16 = lane & 15, quad = lane >> 4;
  const int wm = (wave >> 1) * 64, wn = (wave & 1) * 64;
  for (int i = tid; i < 128; i += 256) css[i] = 0.f;
  __syncthreads();
  long rowbase = (long)bh * 4096 + nt * 128;
  float hnv[4][4];
#pragma unroll
  for (int i = 0; i < 4; i++)
#pragma unroll
    for (int r = 0; r < 4; r++)
      hnv[i][r] = halfnorm[rowbase + wm + i * 16 + quad * 4 + r];
#pragma unroll
  for (int j = 0; j < 4; j++) {
    int col = wn + j * 16 + l16;
    float cp = 0.f;
#pragma unroll
    for (int i = 0; i < 4; i++)
#pragma unroll
      for (int r = 0; r < 4; r++) {
        float v = __expf(acc[i][j][r] - hnv[i][r]) * 0.08838834764831845f;  // /sqrt(128)
        acc[i][j][r] = v;
        cp += v * v;
      }
    atomicAdd(&css[col], cp);
  }
  __syncthreads();
  for (int i = tid; i < 128; i += 256) atomicAdd(&colss[bh * 128 + i], css[i]);
  // transposed write rf -> qnT[bh][m][n], two passes of 64 n
  for (int hh = 0; hh < 2; hh++) {
    __syncthreads();
    if ((wave >> 1) == hh) {
#pragma unroll
      for (int i = 0; i < 4; i++)
#pragma unroll
        for (int j = 0; j < 4; j++)
#pragma unroll
          for (int r = 0; r < 4; r++)
            pool[(i * 16 + quad * 4 + r) * 134 + wn + j * 16 + l16] = f2bf(acc[i][j][r]);
    }
    __syncthreads();
#pragma unroll
    for (int c = 0; c < 4; c++) {
      int chunk = tid + c * 256;
      int m = chunk >> 3, nj = (chunk & 7) * 8;
      unsigned short o[8];
#pragma unroll
      for (int e = 0; e < 8; e++) o[e] = pool[(nj + e) * 134 + m];
      *(uint4*)&qnT[((long)bh * 128 + m) * 4096 + nt * 128 + hh * 64 + nj] = *(uint4*)o;
    }
  }
}

// ---------------- K5: kk|kv NT GEMM, rn-scaled, K-split atomics ----------------
__global__ __launch_bounds__(256) void k_gemm_kkkv(const unsigned short* __restrict__ qnT,
                                                   const unsigned short* __restrict__ vT,
                                                   const float* __restrict__ colss,
                                                   float* __restrict__ kkkv) {
  __shared__ __align__(16) unsigned short As[128 * 32], Bs[192 * 32];
  f32x4 acc[4][6];
  const int ks = blockIdx.x, bh = blockIdx.y;
  const unsigned short* A = qnT + (long)bh * 128 * 4096 + ks * 512;
  const unsigned short* B1 = vT + (long)bh * 64 * 4096 + ks * 512;
  gemm_core_nt<128, 192>(A, 4096, A, B1, 128, 4096, 512, acc, As, Bs);
  const int lane = threadIdx.x & 63, wave = threadIdx.x >> 6;
  const int l16 = lane & 15, quad = lane >> 4;
  const int wm = (wave >> 1) * 64, wn = (wave & 1) * 96;
  float rnr[4][4];
#pragma unroll
  for (int i = 0; i < 4; i++)
#pragma unroll
    for (int r = 0; r < 4; r++)
      rnr[i][r] = rn_of(colss[bh * 128 + wm + i * 16 + quad * 4 + r]);
#pragma unroll
  for (int j = 0; j < 6; j++) {
    int col = wn + j * 16 + l16;
    float rnc = (col < 128) ? rn_of(colss[bh * 128 + col]) : 1.f;
#pragma unroll
    for (int i = 0; i < 4; i++)
#pragma unroll
      for (int r = 0; r < 4; r++) {
        int row = wm + i * 16 + quad * 4 + r;
        atomicAdd(&kkkv[((long)bh * 128 + row) * 192 + col], acc[i][j][r] * rnr[i][r] * rnc);
      }
  }
}

// ---------------- K6: ISTA solve, one block per (b,h); sT scaled by rn[m] ----------------
__global__ __launch_bounds__(256) void k_ista(const float* __restrict__ kkkv,
                                              const float* __restrict__ colss,
                                              unsigned short* __restrict__ sT) {
  __shared__ unsigned short kks[128 * 132];  // kk bf16 (33.8 KB)
  __shared__ unsigned short ss[128 * 64];    // s bf16 (16.4 KB)
  __shared__ float red[128];
  const int tid = threadIdx.x;
  const int bh = blockIdx.x;
  const int d = tid & 63, mg = tid >> 6;
  for (int idx = tid; idx < 128 * 128; idx += 256) {
    int m = idx >> 7, p = idx & 127;
    kks[m * 132 + p] = f2bf(kkkv[((long)bh * 128 + m) * 192 + p]);
  }
  float kv[32];
#pragma unroll
  for (int mi = 0; mi < 32; mi++)
    kv[mi] = kkkv[((long)bh * 128 + mg * 32 + mi) * 192 + 128 + d];
  __syncthreads();
  if (tid < 128) {
    float rs = 0.f;
    for (int p = 0; p < 128; p++) rs += fabsf(bf2f(kks[tid * 132 + p]));
    red[tid] = rs;
  }
  __syncthreads();
  for (int o = 64; o > 0; o >>= 1) {
    if (tid < o) red[tid] = fmaxf(red[tid], red[tid + o]);
    __syncthreads();
  }
  const float L = red[0] + 1.f;
  const float invL = 1.f / L;
  const float lamL = 0.3f * invL;
  float sreg[32];
#pragma unroll
  for (int mi = 0; mi < 32; mi++) {
    float z = kv[mi];
    float az = fabsf(z) - 0.3f;
    sreg[mi] = az > 0.f ? copysignf(az, z) : 0.f;
    ss[(mg * 32 + mi) * 64 + d] = f2bf(sreg[mi]);
  }
  for (int step = 0; step < 5; step++) {
    __syncthreads();
    float a[32];
#pragma unroll
    for (int mi = 0; mi < 32; mi++) a[mi] = 0.f;
    for (int p = 0; p < 128; p += 4) {
      float s0 = bf2f(ss[(p + 0) * 64 + d]);
      float s1 = bf2f(ss[(p + 1) * 64 + d]);
      float s2 = bf2f(ss[(p + 2) * 64 + d]);
      float s3 = bf2f(ss[(p + 3) * 64 + d]);
#pragma unroll
      for (int mi = 0; mi < 32; mi++) {
        union { uint2 u; unsigned short s[4]; } k4;
        k4.u = *(const uint2*)&kks[(mg * 32 + mi) * 132 + p];
        a[mi] += bf2f(k4.s[0]) * s0 + bf2f(k4.s[1]) * s1 + bf2f(k4.s[2]) * s2 + bf2f(k4.s[3]) * s3;
      }
    }
    __syncthreads();
#pragma unroll
    for (int mi = 0; mi < 32; mi++) {
      float z = sreg[mi] - (a[mi] - kv[mi]) * invL;
      float az = fabsf(z) - lamL;
      sreg[mi] = az > 0.f ? copysignf(az, z) : 0.f;
      ss[(mg * 32 + mi) * 64 + d] = f2bf(sreg[mi]);
    }
  }
#pragma unroll
  for (int mi = 0; mi < 32; mi++) {
    float rn = rn_of(colss[bh * 128 + mg * 32 + mi]);  // fold qn scaling into s
    sT[((long)bh * 64 + d) * 128 + mg * 32 + mi] = f2bf(sreg[mi] * rn);
  }
}

// ---------------- K7: attn = rf @ s' (TN over qnT, gather-staged) ----------------
__global__ __launch_bounds__(256) void k_gemm_attn(const unsigned short* __restrict__ qnT,
                                                   const unsigned short* __restrict__ sT,
                                                   unsigned short* __restrict__ attn) {
  __shared__ __align__(16) unsigned short As2[32 * 128];  // [k][n] natural
  __shared__ __align__(16) unsigned short Bs[64 * 32];
  f32x4 acc[4][2];
  const int nt = blockIdx.x, bh = blockIdx.y;
  const int b = bh / 12, h = bh % 12;
  const int tid = threadIdx.x, lane = tid & 63, wave = tid >> 6;
  const int l16 = lane & 15, quad = lane >> 4;
  const int wm = (wave >> 1) * 64, wn = (wave & 1) * 32;
#pragma unroll
  for (int i = 0; i < 4; i++)
#pragma unroll
    for (int j = 0; j < 2; j++)
#pragma unroll
      for (int r = 0; r < 4; r++) acc[i][j][r] = 0.f;
  for (int k0 = 0; k0 < 128; k0 += 32) {
    __syncthreads();
#pragma unroll
    for (int c = 0; c < 2; c++) {
      int chunk = tid + c * 256;
      int kr = chunk >> 4, n0 = (chunk & 15) * 8;
      *(uint4*)&As2[kr * 128 + n0] =
          *(const uint4*)&qnT[((long)bh * 128 + k0 + kr) * 4096 + nt * 128 + n0];
    }
    {
      int dd = tid >> 2, ko = (tid & 3) * 8;
      *(uint4*)&Bs[dd * 32 + ko] = *(const uint4*)&sT[((long)bh * 64 + dd) * 128 + k0 + ko];
    }
    __syncthreads();
    bf16x8 af[4], bfr[2];
#pragma unroll
    for (int i = 0; i < 4; i++) {
      union { bf16x8 v; unsigned short s[8]; } u;
#pragma unroll
      for (int e = 0; e < 8; e++) u.s[e] = As2[(quad * 8 + e) * 128 + wm + i * 16 + l16];
      af[i] = u.v;
    }
#pragma unroll
    for (int j = 0; j < 2; j++)
      bfr[j] = *(const bf16x8*)&Bs[(wn + j * 16 + l16) * 32 + quad * 8];
#pragma unroll
    for (int i = 0; i < 4; i++)
#pragma unroll
      for (int j = 0; j < 2; j++)
        acc[i][j] = __builtin_amdgcn_mfma_f32_16x16x32_bf16(af[i], bfr[j], acc[i][j], 0, 0, 0);
  }
#pragma unroll
  for (int i = 0; i < 4; i++)
#pragma unroll
    for (int j = 0; j < 2; j++)
#pragma unroll
      for (int r = 0; r < 4; r++) {
        int n = nt * 128 + wm + i * 16 + quad * 4 + r;
        int dd = wn + j * 16 + l16;
        attn[((long)b * 4096 + n) * 768 + h * 64 + dd] = f2bf(acc[i][j][r]);
      }
}

// ---------------- K8: out = attn @ Wproj + bias ----------------
__global__ __launch_bounds__(256) void k_gemm_proj(const unsigned short* __restrict__ attn,
                                                   const unsigned short* __restrict__ wprojT,
                                                   const float* __restrict__ bias,
                                                   float* __restrict__ out) {
  __shared__ __align__(16) unsigned short As[128 * 32], Bs[128 * 32];
  f32x4 acc[4][4];
  const unsigned short* A = attn + (long)blockIdx.y * 128 * 768;
  const unsigned short* B = wprojT + (long)blockIdx.x * 128 * 768;
  gemm_core_nt<128, 128>(A, 768, B, B, 128, 768, 768, acc, As, Bs);
  const int lane = threadIdx.x & 63, wave = threadIdx.x >> 6;
  const int l16 = lane & 15, quad = lane >> 4;
  const int wm = (wave >> 1) * 64, wn = (wave & 1) * 64;
  long row0 = (long)blockIdx.y * 128, col0 = (long)blockIdx.x * 128;
#pragma unroll
  for (int i = 0; i < 4; i++)
#pragma unroll
    for (int j = 0; j < 4; j++) {
      int col = (int)col0 + wn + j * 16 + l16;
      float bv = bias[col];
#pragma unroll
      for (int r = 0; r < 4; r++) {
        long row = row0 + wm + i * 16 + quad * 4 + r;
        out[row * 768 + col] = acc[i][j][r] + bv;
      }
    }
}

extern "C" void kernel_launch(void* const* d_in, const int* in_sizes, int n_in,
                              void* d_out, int out_size, void* d_ws, size_t ws_size,
                              hipStream_t stream) {
  const float* x = (const float*)d_in[0];
  const float* Wqkv = (const float*)d_in[1];
  const float* Wproj = (const float*)d_in[2];
  const float* bproj = (const float*)d_in[3];
  const float* rm = (const float*)d_in[4];
  float* out = (float*)d_out;

  size_t o = 0;
  char* wsb = (char*)d_ws;
  auto take = [&](size_t b) { char* p = wsb + o; o += b; return p; };
  unsigned short* wqkvT = (unsigned short*)take(2359296);
  unsigned short* wprojT = (unsigned short*)take(1179648);
  unsigned short* rmT = (unsigned short*)take(196608);
  unsigned short* q = (unsigned short*)take(50331648);    // reused as attn after K3
  unsigned short* vT = (unsigned short*)take(50331648);
  float* halfnorm = (float*)take(1572864);
  float* colss = (float*)take(49152);
  float* kkkv = (float*)take(9437184);
  unsigned short* sT = (unsigned short*)take(1572864);
  // total = 117,030,912 B (~112 MB)
  if (ws_size < o) return;

  unsigned short* qnT = (unsigned short*)d_out;  // 100,663,296 B == out bytes; dead before K8
  unsigned short* attnbf = q;                     // alias: q dead after K3

  hipMemsetAsync(colss, 0, 49152, stream);
  hipMemsetAsync(kkkv, 0, 9437184, stream);

  k_transpose_bf16<<<dim3(4608, 1), 256, 0, stream>>>(Wqkv, wqkvT, 768, 1536, 1.0f);
  k_transpose_bf16<<<dim3(2304, 1), 256, 0, stream>>>(Wproj, wprojT, 768, 768, 1.0f);
  // fold qs = q * scale^0.5 into rand_matrix (scale^0.5 = 8^-0.5)
  k_transpose_bf16<<<dim3(32, 12), 256, 0, stream>>>(rm, rmT, 64, 128, 0.3535533905932738f);
  k_gemm_qkv<<<dim3(12, 256), 256, 0, stream>>>(x, wqkvT, q, vT);
  k_halfnorm<<<dim3(16, 96), 256, 0, stream>>>(q, halfnorm);
  k_gemm_rf<<<dim3(32, 96), 256, 0, stream>>>(q, rmT, halfnorm, qnT, colss);
  k_gemm_kkkv<<<dim3(8, 96), 256, 0, stream>>>(qnT, vT, colss, kkkv);
  k_ista<<<96, 256, 0, stream>>>(kkkv, colss, sT);
  k_gemm_attn<<<dim3(32, 96), 256, 0, stream>>>(qnT, sT, attnbf);
  k_gemm_proj<<<dim3(6, 256), 256, 0, stream>>>(attnbf, wprojT, bproj, out);
}

// Round 3
// 524.434 us; speedup vs baseline: 1.4236x; 1.4236x over previous
//
#include <hip/hip_runtime.h>

// ---------------------------------------------------------------------------
// VARS_D: fused linear-attention block on gfx950. Round 3.
//  - x pre-converted to bf16 (lives in d_out[0..48MB); dead before qnT claims d_out)
//  - global_load_lds(16B) staging in all big GEMMs (m97 ladder)
//  - XCD-aware swizzle on K1/K8 so column-tiles of a row-tile share one XCD L2
//  - halfnorm folded into rf GEMM (full-tile staged, row sumsq from LDS)
//  - ISTA rewritten with MFMA (kk/ssT in LDS, s in C-layout registers)
// ---------------------------------------------------------------------------

typedef __attribute__((ext_vector_type(8))) short bf16x8;
typedef __attribute__((ext_vector_type(4))) float f32x4;

#define GLD16(gptr, lptr)                                                              \
  __builtin_amdgcn_global_load_lds((const __attribute__((address_space(1))) void*)(gptr), \
                                   (__attribute__((address_space(3))) void*)(lptr), 16, 0, 0)

__device__ __forceinline__ unsigned short f2bf(float f) {
  union { float f; unsigned int u; } v; v.f = f;
  unsigned int r = v.u + 0x7fffu + ((v.u >> 16) & 1u);   // RNE
  return (unsigned short)(r >> 16);
}
__device__ __forceinline__ float bf2f(unsigned short s) {
  union { unsigned int u; float f; } v; v.u = ((unsigned int)s) << 16;
  return v.f;
}
__device__ __forceinline__ float rn_of(float css) {
  return 1.f / fmaxf(sqrtf(css), 1e-12f);
}

// NT GEMM core: C[M,N] += A[M,K] * B^T[N,K], bf16, fp32 acc, gld staging.
// LDS layout: chunk-linear, 16B/lane (global_load_lds wave-uniform base + lane*16).
template<int BM, int BN>
__device__ __forceinline__ void gemm_core_nt(
    const unsigned short* __restrict__ A, int lda,
    const unsigned short* __restrict__ B0,
    const unsigned short* __restrict__ B1, int brows0, int ldb,
    int K,
    f32x4 (&acc)[BM / 32][BN / 32],
    unsigned short* As, unsigned short* Bs) {
  constexpr int MT = BM / 32, NT = BN / 32;
  const int tid = threadIdx.x;
  const int lane = tid & 63, wave = tid >> 6;
  const int wm = (wave >> 1) * (BM / 2), wn = (wave & 1) * (BN / 2);
  const int l16 = lane & 15, quad = lane >> 4;
  const int arow = tid >> 2, ako = (tid & 3) << 3;
#pragma unroll
  for (int i = 0; i < MT; i++)
#pragma unroll
    for (int j = 0; j < NT; j++)
#pragma unroll
      for (int r = 0; r < 4; r++) acc[i][j][r] = 0.f;

  for (int k0 = 0; k0 < K; k0 += 32) {
    __syncthreads();
#pragma unroll
    for (int c = 0; c < BM / 64; c++) {
      const unsigned short* gp = A + (long)(arow + c * 64) * lda + k0 + ako;
      GLD16(gp, As + (c * 256 + wave * 64) * 8);
    }
#pragma unroll
    for (int c = 0; c < BN / 64; c++) {
      int row = arow + c * 64;
      const unsigned short* bp = (row < brows0) ? (B0 + (long)row * ldb)
                                                : (B1 + (long)(row - brows0) * ldb);
      GLD16(bp + k0 + ako, Bs + (c * 256 + wave * 64) * 8);
    }
    __syncthreads();
    bf16x8 af[MT], bfr[NT];
#pragma unroll
    for (int i = 0; i < MT; i++)
      af[i] = *(const bf16x8*)(As + (wm + i * 16 + l16) * 32 + quad * 8);
#pragma unroll
    for (int j = 0; j < NT; j++)
      bfr[j] = *(const bf16x8*)(Bs + (wn + j * 16 + l16) * 32 + quad * 8);
#pragma unroll
    for (int i = 0; i < MT; i++)
#pragma unroll
      for (int j = 0; j < NT; j++)
        acc[i][j] = __builtin_amdgcn_mfma_f32_16x16x32_bf16(af[i], bfr[j], acc[i][j], 0, 0, 0);
  }
}

// ---------------- convert: fp32 -> bf16 ----------------
__global__ __launch_bounds__(256) void k_convert_bf16(const float* __restrict__ in,
                                                      unsigned short* __restrict__ out, long n4) {
  long i = (long)blockIdx.x * 256 + threadIdx.x;
  if (i < n4) {
    float4 v = ((const float4*)in)[i];
    unsigned short o[4] = {f2bf(v.x), f2bf(v.y), f2bf(v.z), f2bf(v.w)};
    ((uint2*)out)[i] = *(uint2*)o;
  }
}

// ---------------- T: batched transpose fp32[R,C] -> bf16[C,R] ----------------
__global__ __launch_bounds__(256) void k_transpose_bf16(const float* __restrict__ in,
                                                        unsigned short* __restrict__ out,
                                                        int R, int C, float scale) {
  int b = blockIdx.y;
  long base = (long)b * R * C;
  long idx = (long)blockIdx.x * 256 + threadIdx.x;
  if (idx < (long)R * C) {
    int oc = (int)(idx / R);
    int orr = (int)(idx - (long)oc * R);
    out[base + idx] = f2bf(in[base + (long)orr * C + oc] * scale);
  }
}

// ---------------- K1: qkv GEMM (xbf bf16), XCD-swizzled grid ----------------
__global__ __launch_bounds__(256) void k_gemm_qkv(const unsigned short* __restrict__ xbf,
                                                  const unsigned short* __restrict__ wqkvT,
                                                  unsigned short* __restrict__ q,
                                                  unsigned short* __restrict__ vT) {
  __shared__ __align__(16) unsigned short pool[8576];  // As|Bs, then v-transpose
  unsigned short* As = pool;
  unsigned short* Bs = pool + 4096;
  f32x4 acc[4][4];
  const int L = blockIdx.x;
  const int xcd = L & 7, slot = L >> 3;
  const int rt = xcd * 32 + slot / 12;   // all 12 ct of one rt -> same XCD
  const int ct = slot % 12;
  const int tid = threadIdx.x, lane = tid & 63, wave = tid >> 6;
  const int l16 = lane & 15, quad = lane >> 4;
  const int wm = (wave >> 1) * 64, wn = (wave & 1) * 64;

  const unsigned short* A = xbf + (long)rt * 128 * 768;
  const unsigned short* B = wqkvT + (long)ct * 128 * 768;
  gemm_core_nt<128, 128>(A, 768, B, B, 128, 768, 768, acc, As, Bs);

  const int b = rt >> 5;
  const int nbase = (rt & 31) * 128;
  if (ct < 6) {  // q columns -> [bh][n][d]
#pragma unroll
    for (int i = 0; i < 4; i++)
#pragma unroll
      for (int j = 0; j < 4; j++)
#pragma unroll
        for (int r = 0; r < 4; r++) {
          int col = ct * 128 + wn + j * 16 + l16;
          int h = col >> 6, d = col & 63;
          int n = nbase + wm + i * 16 + quad * 4 + r;
          q[((long)(b * 12 + h) * 4096 + n) * 64 + d] = f2bf(acc[i][j][r]);
        }
  } else {  // v columns: LDS transpose -> vT[bh][d][n]
    for (int hh = 0; hh < 2; hh++) {
      __syncthreads();
      if ((wave >> 1) == hh) {
#pragma unroll
        for (int i = 0; i < 4; i++)
#pragma unroll
          for (int j = 0; j < 4; j++)
#pragma unroll
            for (int r = 0; r < 4; r++)
              pool[(i * 16 + quad * 4 + r) * 134 + wn + j * 16 + l16] = f2bf(acc[i][j][r]);
      }
      __syncthreads();
#pragma unroll
      for (int c = 0; c < 4; c++) {
        int chunk = tid + c * 256;
        int col = chunk >> 3, nj = (chunk & 7) * 8;
        unsigned short o[8];
#pragma unroll
        for (int e = 0; e < 8; e++) o[e] = pool[(nj + e) * 134 + col];
        int vcol = ct * 128 - 768 + col;
        int h = vcol >> 6, d = vcol & 63;
        long n = nbase + hh * 64 + nj;
        *(uint4*)&vT[((long)(b * 12 + h) * 64 + d) * 4096 + n] = *(uint4*)o;
      }
    }
  }
}

// ---------------- K3: rf GEMM, full-tile staged, halfnorm folded ----------------
__global__ __launch_bounds__(256) void k_gemm_rf(const unsigned short* __restrict__ q,
                                                 const unsigned short* __restrict__ rmT,
                                                 unsigned short* __restrict__ qnT,
                                                 float* __restrict__ colss) {
  __shared__ __align__(16) unsigned short smem[16384];  // A panels | B panels; pool reuses
  __shared__ float hnp[256];
  __shared__ float css[128];
  unsigned short* Asm = smem;          // 2 panels of 128x32
  unsigned short* Bsm = smem + 8192;   // 2 panels of 128x32
  unsigned short* pool = smem;         // 64x134 transpose buffer (reuses A/B)
  f32x4 acc[4][4];
  const int nt = blockIdx.x, bh = blockIdx.y, h = bh % 12;
  const int tid = threadIdx.x, lane = tid & 63, wave = tid >> 6;
  const int l16 = lane & 15, quad = lane >> 4;
  const int wm = (wave >> 1) * 64, wn = (wave & 1) * 64;
  const unsigned short* Aq = q + ((long)bh * 4096 + nt * 128) * 64;
  const unsigned short* Brm = rmT + (long)h * 8192;

#pragma unroll
  for (int c = 0; c < 4; c++) {  // stage full 128x64 A and B (panelized BK=32)
    int chunk = c * 256 + tid;
    int row = chunk >> 3, ko8 = chunk & 7;
    int kc = ko8 >> 2, kw = (ko8 & 3) * 8;
    *(uint4*)(Asm + kc * 4096 + row * 32 + kw) = *(const uint4*)(Aq + (long)row * 64 + ko8 * 8);
    *(uint4*)(Bsm + kc * 4096 + row * 32 + kw) = *(const uint4*)(Brm + (long)row * 64 + ko8 * 8);
  }
  for (int i = tid; i < 128; i += 256) css[i] = 0.f;
  __syncthreads();
  {  // halfnorm partials from staged q tile: thread = (row, panel)
    const unsigned short* ap = Asm + (tid & 1) * 4096 + (tid >> 1) * 32;
    float ssum = 0.f;
#pragma unroll
    for (int e = 0; e < 32; e++) { float f = bf2f(ap[e]); ssum += f * f; }
    hnp[tid] = ssum;
  }
#pragma unroll
  for (int i = 0; i < 4; i++)
#pragma unroll
    for (int j = 0; j < 4; j++)
#pragma unroll
      for (int r = 0; r < 4; r++) acc[i][j][r] = 0.f;
#pragma unroll
  for (int kc = 0; kc < 2; kc++) {
    bf16x8 af[4], bfr[4];
#pragma unroll
    for (int i = 0; i < 4; i++)
      af[i] = *(const bf16x8*)(Asm + kc * 4096 + (wm + i * 16 + l16) * 32 + quad * 8);
#pragma unroll
    for (int j = 0; j < 4; j++)
      bfr[j] = *(const bf16x8*)(Bsm + kc * 4096 + (wn + j * 16 + l16) * 32 + quad * 8);
#pragma unroll
    for (int i = 0; i < 4; i++)
#pragma unroll
      for (int j = 0; j < 4; j++)
        acc[i][j] = __builtin_amdgcn_mfma_f32_16x16x32_bf16(af[i], bfr[j], acc[i][j], 0, 0, 0);
  }
  __syncthreads();  // hnp ready; MFMA reads of smem done (pool will reuse)
  float hnv[4][4];
#pragma unroll
  for (int i = 0; i < 4; i++)
#pragma unroll
    for (int r = 0; r < 4; r++) {
      int row = wm + i * 16 + quad * 4 + r;
      hnv[i][r] = 0.0625f * (hnp[2 * row] + hnp[2 * row + 1]);  // 0.5*scale*||q||^2
    }
#pragma unroll
  for (int j = 0; j < 4; j++) {
    int col = wn + j * 16 + l16;
    float cp = 0.f;
#pragma unroll
    for (int i = 0; i < 4; i++)
#pragma unroll
      for (int r = 0; r < 4; r++) {
        float v = __expf(acc[i][j][r] - hnv[i][r]) * 0.08838834764831845f;  // /sqrt(128)
        acc[i][j][r] = v;
        cp += v * v;
      }
    atomicAdd(&css[col], cp);
  }
  __syncthreads();
  for (int i = tid; i < 128; i += 256) atomicAdd(&colss[bh * 128 + i], css[i]);
  // transposed write rf -> qnT[bh][m][n]
  for (int hh = 0; hh < 2; hh++) {
    __syncthreads();
    if ((wave >> 1) == hh) {
#pragma unroll
      for (int i = 0; i < 4; i++)
#pragma unroll
        for (int j = 0; j < 4; j++)
#pragma unroll
          for (int r = 0; r < 4; r++)
            pool[(i * 16 + quad * 4 + r) * 134 + wn + j * 16 + l16] = f2bf(acc[i][j][r]);
    }
    __syncthreads();
#pragma unroll
    for (int c = 0; c < 4; c++) {
      int chunk = tid + c * 256;
      int m = chunk >> 3, nj = (chunk & 7) * 8;
      unsigned short o[8];
#pragma unroll
      for (int e = 0; e < 8; e++) o[e] = pool[(nj + e) * 134 + m];
      *(uint4*)&qnT[((long)bh * 128 + m) * 4096 + nt * 128 + hh * 64 + nj] = *(uint4*)o;
    }
  }
}

// ---------------- K5: kk|kv NT GEMM, rn-scaled, K-split atomics ----------------
__global__ __launch_bounds__(256) void k_gemm_kkkv(const unsigned short* __restrict__ qnT,
                                                   const unsigned short* __restrict__ vT,
                                                   const float* __restrict__ colss,
                                                   float* __restrict__ kkkv) {
  __shared__ __align__(16) unsigned short As[128 * 32], Bs[192 * 32];
  f32x4 acc[4][6];
  const int ks = blockIdx.x, bh = blockIdx.y;
  const unsigned short* A = qnT + (long)bh * 128 * 4096 + ks * 512;
  const unsigned short* B1 = vT + (long)bh * 64 * 4096 + ks * 512;
  gemm_core_nt<128, 192>(A, 4096, A, B1, 128, 4096, 512, acc, As, Bs);
  const int lane = threadIdx.x & 63, wave = threadIdx.x >> 6;
  const int l16 = lane & 15, quad = lane >> 4;
  const int wm = (wave >> 1) * 64, wn = (wave & 1) * 96;
  float rnr[4][4];
#pragma unroll
  for (int i = 0; i < 4; i++)
#pragma unroll
    for (int r = 0; r < 4; r++)
      rnr[i][r] = rn_of(colss[bh * 128 + wm + i * 16 + quad * 4 + r]);
#pragma unroll
  for (int j = 0; j < 6; j++) {
    int col = wn + j * 16 + l16;
    float rnc = (col < 128) ? rn_of(colss[bh * 128 + col]) : 1.f;
#pragma unroll
    for (int i = 0; i < 4; i++)
#pragma unroll
      for (int r = 0; r < 4; r++) {
        int row = wm + i * 16 + quad * 4 + r;
        atomicAdd(&kkkv[((long)bh * 128 + row) * 192 + col], acc[i][j][r] * rnr[i][r] * rnc);
      }
  }
}

// ---------------- K6: ISTA via MFMA; s in C-layout regs, ssT in LDS ----------------
__global__ __launch_bounds__(256) void k_ista(const float* __restrict__ kkkv,
                                              const float* __restrict__ colss,
                                              unsigned short* __restrict__ sT) {
  __shared__ __align__(16) unsigned short kks[128 * 144];  // kk bf16, pitch 144 (16B-aligned rows)
  __shared__ __align__(16) unsigned short ssT[64 * 144];   // s^T bf16 [d][p]
  __shared__ float red[128];
  __shared__ float rns[128];
  const int tid = threadIdx.x, lane = tid & 63, wave = tid >> 6;
  const int l16 = lane & 15, quad = lane >> 4;
  const int wm = (wave >> 1) * 64, wn = (wave & 1) * 32;
  const int bh = blockIdx.x;
  const float* kkb = kkkv + (long)bh * 128 * 192;
  for (int idx = tid; idx < 128 * 32; idx += 256) {  // kk fp32 -> bf16 LDS
    int m = idx >> 5, p4 = (idx & 31) * 4;
    float4 v = *(const float4*)(kkb + (long)m * 192 + p4);
    unsigned short o[4] = {f2bf(v.x), f2bf(v.y), f2bf(v.z), f2bf(v.w)};
    *(uint2*)(kks + m * 144 + p4) = *(uint2*)o;
  }
  float kv[4][2][4];
#pragma unroll
  for (int i = 0; i < 4; i++)
#pragma unroll
    for (int j = 0; j < 2; j++)
#pragma unroll
      for (int r = 0; r < 4; r++) {
        int m = wm + i * 16 + quad * 4 + r, d = wn + j * 16 + l16;
        kv[i][j][r] = kkb[(long)m * 192 + 128 + d];
      }
  __syncthreads();
  if (tid < 128) {  // row L1 norms + rn
    float rs = 0.f;
    const unsigned short* rp = kks + tid * 144;
    for (int p = 0; p < 128; p++) rs += fabsf(bf2f(rp[p]));
    red[tid] = rs;
    rns[tid] = rn_of(colss[bh * 128 + tid]);
  }
  __syncthreads();
  for (int o = 64; o > 0; o >>= 1) {
    if (tid < o) red[tid] = fmaxf(red[tid], red[tid + o]);
    __syncthreads();
  }
  const float L = red[0] + 1.f;
  const float invL = 1.f / L;
  const float lamL = 0.3f * invL;
  float sreg[4][2][4];
#pragma unroll
  for (int i = 0; i < 4; i++)
#pragma unroll
    for (int j = 0; j < 2; j++)
#pragma unroll
      for (int r = 0; r < 4; r++) {
        float z = kv[i][j][r];
        float az = fabsf(z) - 0.3f;
        float s = az > 0.f ? copysignf(az, z) : 0.f;
        sreg[i][j][r] = s;
        ssT[(wn + j * 16 + l16) * 144 + wm + i * 16 + quad * 4 + r] = f2bf(s);
      }
  for (int step = 0; step < 5; step++) {
    __syncthreads();  // all ssT writes visible
    f32x4 acc[4][2];
#pragma unroll
    for (int i = 0; i < 4; i++)
#pragma unroll
      for (int j = 0; j < 2; j++)
#pragma unroll
        for (int r = 0; r < 4; r++) acc[i][j][r] = 0.f;
#pragma unroll
    for (int kc = 0; kc < 4; kc++) {
      bf16x8 af[4], bfj[2];
#pragma unroll
      for (int i = 0; i < 4; i++)
        af[i] = *(const bf16x8*)(kks + (wm + i * 16 + l16) * 144 + kc * 32 + quad * 8);
#pragma unroll
      for (int j = 0; j < 2; j++)
        bfj[j] = *(const bf16x8*)(ssT + (wn + j * 16 + l16) * 144 + kc * 32 + quad * 8);
#pragma unroll
      for (int i = 0; i < 4; i++)
#pragma unroll
        for (int j = 0; j < 2; j++)
          acc[i][j] = __builtin_amdgcn_mfma_f32_16x16x32_bf16(af[i], bfj[j], acc[i][j], 0, 0, 0);
    }
    __syncthreads();  // all reads done before rewriting ssT
#pragma unroll
    for (int i = 0; i < 4; i++)
#pragma unroll
      for (int j = 0; j < 2; j++)
#pragma unroll
        for (int r = 0; r < 4; r++) {
          float z = sreg[i][j][r] - (acc[i][j][r] - kv[i][j][r]) * invL;
          float az = fabsf(z) - lamL;
          float s = az > 0.f ? copysignf(az, z) : 0.f;
          sreg[i][j][r] = s;
          ssT[(wn + j * 16 + l16) * 144 + wm + i * 16 + quad * 4 + r] = f2bf(s);
        }
  }
#pragma unroll
  for (int i = 0; i < 4; i++)
#pragma unroll
    for (int j = 0; j < 2; j++)
#pragma unroll
      for (int r = 0; r < 4; r++) {
        int m = wm + i * 16 + quad * 4 + r, d = wn + j * 16 + l16;
        sT[(long)bh * 8192 + d * 128 + m] = f2bf(sreg[i][j][r] * rns[m]);  // fold rn[m]
      }
}

// ---------------- K7: attn = qn @ s (TN over qnT, gather-staged) ----------------
__global__ __launch_bounds__(256) void k_gemm_attn(const unsigned short* __restrict__ qnT,
                                                   const unsigned short* __restrict__ sT,
                                                   unsigned short* __restrict__ attn) {
  __shared__ __align__(16) unsigned short As2[32 * 128];  // [k][n]
  __shared__ __align__(16) unsigned short Bs[64 * 32];
  f32x4 acc[4][2];
  const int nt = blockIdx.x, bh = blockIdx.y;
  const int b = bh / 12, h = bh % 12;
  const int tid = threadIdx.x, lane = tid & 63, wave = tid >> 6;
  const int l16 = lane & 15, quad = lane >> 4;
  const int wm = (wave >> 1) * 64, wn = (wave & 1) * 32;
#pragma unroll
  for (int i = 0; i < 4; i++)
#pragma unroll
    for (int j = 0; j < 2; j++)
#pragma unroll
      for (int r = 0; r < 4; r++) acc[i][j][r] = 0.f;
  for (int k0 = 0; k0 < 128; k0 += 32) {
    __syncthreads();
#pragma unroll
    for (int c = 0; c < 2; c++) {
      int chunk = tid + c * 256;
      int kr = chunk >> 4, n0 = (chunk & 15) * 8;
      const unsigned short* gp = qnT + ((long)bh * 128 + k0 + kr) * 4096 + nt * 128 + n0;
      GLD16(gp, As2 + (c * 256 + wave * 64) * 8);
    }
    {
      int dd = tid >> 2, ko = (tid & 3) * 8;
      const unsigned short* gp = sT + ((long)bh * 64 + dd) * 128 + k0 + ko;
      GLD16(gp, Bs + wave * 512);
    }
    __syncthreads();
    bf16x8 af[4], bfr[2];
#pragma unroll
    for (int i = 0; i < 4; i++) {
      union { bf16x8 v; unsigned short s[8]; } u;
#pragma unroll
      for (int e = 0; e < 8; e++) u.s[e] = As2[(quad * 8 + e) * 128 + wm + i * 16 + l16];
      af[i] = u.v;
    }
#pragma unroll
    for (int j = 0; j < 2; j++)
      bfr[j] = *(const bf16x8*)&Bs[(wn + j * 16 + l16) * 32 + quad * 8];
#pragma unroll
    for (int i = 0; i < 4; i++)
#pragma unroll
      for (int j = 0; j < 2; j++)
        acc[i][j] = __builtin_amdgcn_mfma_f32_16x16x32_bf16(af[i], bfr[j], acc[i][j], 0, 0, 0);
  }
#pragma unroll
  for (int i = 0; i < 4; i++)
#pragma unroll
    for (int j = 0; j < 2; j++)
#pragma unroll
      for (int r = 0; r < 4; r++) {
        int n = nt * 128 + wm + i * 16 + quad * 4 + r;
        int dd = wn + j * 16 + l16;
        attn[((long)b * 4096 + n) * 768 + h * 64 + dd] = f2bf(acc[i][j][r]);
      }
}

// ---------------- K8: out = attn @ Wproj + bias, XCD-swizzled ----------------
__global__ __launch_bounds__(256) void k_gemm_proj(const unsigned short* __restrict__ attn,
                                                   const unsigned short* __restrict__ wprojT,
                                                   const float* __restrict__ bias,
                                                   float* __restrict__ out) {
  __shared__ __align__(16) unsigned short As[128 * 32], Bs[128 * 32];
  f32x4 acc[4][4];
  const int Lb = blockIdx.x;
  const int xcd = Lb & 7, slot = Lb >> 3;
  const int rt = xcd * 32 + slot / 6;
  const int ct = slot % 6;
  const unsigned short* A = attn + (long)rt * 128 * 768;
  const unsigned short* B = wprojT + (long)ct * 128 * 768;
  gemm_core_nt<128, 128>(A, 768, B, B, 128, 768, 768, acc, As, Bs);
  const int lane = threadIdx.x & 63, wave = threadIdx.x >> 6;
  const int l16 = lane & 15, quad = lane >> 4;
  const int wm = (wave >> 1) * 64, wn = (wave & 1) * 64;
  long row0 = (long)rt * 128, col0 = (long)ct * 128;
#pragma unroll
  for (int i = 0; i < 4; i++)
#pragma unroll
    for (int j = 0; j < 4; j++) {
      int col = (int)col0 + wn + j * 16 + l16;
      float bv = bias[col];
#pragma unroll
      for (int r = 0; r < 4; r++) {
        long row = row0 + wm + i * 16 + quad * 4 + r;
        out[row * 768 + col] = acc[i][j][r] + bv;
      }
    }
}

extern "C" void kernel_launch(void* const* d_in, const int* in_sizes, int n_in,
                              void* d_out, int out_size, void* d_ws, size_t ws_size,
                              hipStream_t stream) {
  const float* x = (const float*)d_in[0];
  const float* Wqkv = (const float*)d_in[1];
  const float* Wproj = (const float*)d_in[2];
  const float* bproj = (const float*)d_in[3];
  const float* rm = (const float*)d_in[4];
  float* out = (float*)d_out;

  size_t o = 0;
  char* wsb = (char*)d_ws;
  auto take = [&](size_t b) { char* p = wsb + o; o += b; return p; };
  unsigned short* wqkvT = (unsigned short*)take(2359296);
  unsigned short* wprojT = (unsigned short*)take(1179648);
  unsigned short* rmT = (unsigned short*)take(196608);
  unsigned short* q = (unsigned short*)take(50331648);    // reused as attn after K3
  unsigned short* vT = (unsigned short*)take(50331648);
  float* colss = (float*)take(49152);
  float* kkkv = (float*)take(9437184);
  unsigned short* sT = (unsigned short*)take(1572864);
  // total = 115,458,048 B (~110 MB, <= proven round-2 footprint)
  if (ws_size < o) return;

  unsigned short* xbf = (unsigned short*)d_out;  // 48 MB; dead before qnT claims d_out
  unsigned short* qnT = (unsigned short*)d_out;  // 100.66 MB == out bytes; dead before K8
  unsigned short* attnbf = q;                    // alias: q dead after K3

  hipMemsetAsync(colss, 0, 49152, stream);
  hipMemsetAsync(kkkv, 0, 9437184, stream);

  k_convert_bf16<<<24576, 256, 0, stream>>>(x, xbf, 6291456L);
  k_transpose_bf16<<<dim3(4608, 1), 256, 0, stream>>>(Wqkv, wqkvT, 768, 1536, 1.0f);
  k_transpose_bf16<<<dim3(2304, 1), 256, 0, stream>>>(Wproj, wprojT, 768, 768, 1.0f);
  // fold qs = q * scale^0.5 into rand_matrix (scale^0.5 = 8^-0.5)
  k_transpose_bf16<<<dim3(32, 12), 256, 0, stream>>>(rm, rmT, 64, 128, 0.3535533905932738f);
  k_gemm_qkv<<<3072, 256, 0, stream>>>(xbf, wqkvT, q, vT);
  k_gemm_rf<<<dim3(32, 96), 256, 0, stream>>>(q, rmT, qnT, colss);
  k_gemm_kkkv<<<dim3(8, 96), 256, 0, stream>>>(qnT, vT, colss, kkkv);
  k_ista<<<96, 256, 0, stream>>>(kkkv, colss, sT);
  k_gemm_attn<<<dim3(32, 96), 256, 0, stream>>>(qnT, sT, attnbf);
  k_gemm_proj<<<1536, 256, 0, stream>>>(attnbf, wprojT, bproj, out);
}

// Round 4
// 478.458 us; speedup vs baseline: 1.5604x; 1.0961x over previous
//
#include <hip/hip_runtime.h>

// ---------------------------------------------------------------------------
// VARS_D: fused linear-attention block on gfx950. Round 4.
//  - XOR k-chunk swizzle on all MFMA LDS staging (kills 8-way ds_read_b128
//    bank conflicts; producer folds swizzle into gld address so the
//    wave-uniform-base constraint of global_load_lds is preserved)
//  - kkkv: atomics removed -> bf16 K-split partials (aliased in dead q buf),
//    reduced in fp32 inside ISTA
//  - LDS-tiled weight transposes
// ---------------------------------------------------------------------------

typedef __attribute__((ext_vector_type(8))) short bf16x8;
typedef __attribute__((ext_vector_type(4))) float f32x4;

#define GLD16(gptr, lptr)                                                              \
  __builtin_amdgcn_global_load_lds((const __attribute__((address_space(1))) void*)(gptr), \
                                   (__attribute__((address_space(3))) void*)(lptr), 16, 0, 0)

__device__ __forceinline__ unsigned short f2bf(float f) {
  union { float f; unsigned int u; } v; v.f = f;
  unsigned int r = v.u + 0x7fffu + ((v.u >> 16) & 1u);   // RNE
  return (unsigned short)(r >> 16);
}
__device__ __forceinline__ float bf2f(unsigned short s) {
  union { unsigned int u; float f; } v; v.u = ((unsigned int)s) << 16;
  return v.f;
}
__device__ __forceinline__ float rn_of(float css) {
  return 1.f / fmaxf(sqrtf(css), 1e-12f);
}

// NT GEMM core: C[M,N] += A[M,K] * B^T[N,K], bf16, fp32 acc, gld staging.
// LDS: chunk-linear rows of 32 (4 chunks x 8 bf16); chunk position XOR-swizzled
// by ((row>>1)&3) so b128 frag reads hit all 32 banks (2 lanes/bank = free).
template<int BM, int BN>
__device__ __forceinline__ void gemm_core_nt(
    const unsigned short* __restrict__ A, int lda,
    const unsigned short* __restrict__ B0,
    const unsigned short* __restrict__ B1, int brows0, int ldb,
    int K,
    f32x4 (&acc)[BM / 32][BN / 32],
    unsigned short* As, unsigned short* Bs) {
  constexpr int MT = BM / 32, NT = BN / 32;
  const int tid = threadIdx.x;
  const int lane = tid & 63, wave = tid >> 6;
  const int wm = (wave >> 1) * (BM / 2), wn = (wave & 1) * (BN / 2);
  const int l16 = lane & 15, quad = lane >> 4;
  const int arow = tid >> 2;
  const int akos = (((tid & 3) ^ ((arow >> 1) & 3)) << 3);  // swizzled k-offset
  const int fsw = (l16 >> 1) & 3;                            // frag-read swizzle
#pragma unroll
  for (int i = 0; i < MT; i++)
#pragma unroll
    for (int j = 0; j < NT; j++)
#pragma unroll
      for (int r = 0; r < 4; r++) acc[i][j][r] = 0.f;

  for (int k0 = 0; k0 < K; k0 += 32) {
    __syncthreads();
#pragma unroll
    for (int c = 0; c < BM / 64; c++) {
      const unsigned short* gp = A + (long)(arow + c * 64) * lda + k0 + akos;
      GLD16(gp, As + (c * 256 + wave * 64) * 8);
    }
#pragma unroll
    for (int c = 0; c < BN / 64; c++) {
      int row = arow + c * 64;
      const unsigned short* bp = (row < brows0) ? (B0 + (long)row * ldb)
                                                : (B1 + (long)(row - brows0) * ldb);
      GLD16(bp + k0 + akos, Bs + (c * 256 + wave * 64) * 8);
    }
    __syncthreads();
    bf16x8 af[MT], bfr[NT];
#pragma unroll
    for (int i = 0; i < MT; i++)
      af[i] = *(const bf16x8*)(As + (wm + i * 16 + l16) * 32 + ((quad ^ fsw) * 8));
#pragma unroll
    for (int j = 0; j < NT; j++)
      bfr[j] = *(const bf16x8*)(Bs + (wn + j * 16 + l16) * 32 + ((quad ^ fsw) * 8));
#pragma unroll
    for (int i = 0; i < MT; i++)
#pragma unroll
      for (int j = 0; j < NT; j++)
        acc[i][j] = __builtin_amdgcn_mfma_f32_16x16x32_bf16(af[i], bfr[j], acc[i][j], 0, 0, 0);
  }
}

// ---------------- convert: fp32 -> bf16 ----------------
__global__ __launch_bounds__(256) void k_convert_bf16(const float* __restrict__ in,
                                                      unsigned short* __restrict__ out, long n4) {
  long i = (long)blockIdx.x * 256 + threadIdx.x;
  if (i < n4) {
    float4 v = ((const float4*)in)[i];
    unsigned short o[4] = {f2bf(v.x), f2bf(v.y), f2bf(v.z), f2bf(v.w)};
    ((uint2*)out)[i] = *(uint2*)o;
  }
}

// ---------------- T: tiled batched transpose fp32[R,C] -> bf16[C,R] ----------------
__global__ __launch_bounds__(256) void k_transpose_tiled(const float* __restrict__ in,
                                                         unsigned short* __restrict__ out,
                                                         int R, int C, float scale) {
  __shared__ float t[32][33];
  const float* ib = in + (long)blockIdx.z * R * C;
  unsigned short* ob = out + (long)blockIdx.z * R * C;
  int c0 = blockIdx.x * 32, r0 = blockIdx.y * 32;
  int tx = threadIdx.x & 31, ty = threadIdx.x >> 5;
#pragma unroll
  for (int k = 0; k < 32; k += 8)
    t[ty + k][tx] = ib[(long)(r0 + ty + k) * C + c0 + tx];
  __syncthreads();
#pragma unroll
  for (int k = 0; k < 32; k += 8)
    ob[(long)(c0 + ty + k) * R + r0 + tx] = f2bf(t[tx][ty + k] * scale);
}

// ---------------- K1: qkv GEMM (xbf bf16), XCD-swizzled grid ----------------
__global__ __launch_bounds__(256) void k_gemm_qkv(const unsigned short* __restrict__ xbf,
                                                  const unsigned short* __restrict__ wqkvT,
                                                  unsigned short* __restrict__ q,
                                                  unsigned short* __restrict__ vT) {
  __shared__ __align__(16) unsigned short pool[8576];  // As|Bs, then v-transpose
  unsigned short* As = pool;
  unsigned short* Bs = pool + 4096;
  f32x4 acc[4][4];
  const int L = blockIdx.x;
  const int xcd = L & 7, slot = L >> 3;
  const int rt = xcd * 32 + slot / 12;   // all 12 ct of one rt -> same XCD
  const int ct = slot % 12;
  const int tid = threadIdx.x, lane = tid & 63, wave = tid >> 6;
  const int l16 = lane & 15, quad = lane >> 4;
  const int wm = (wave >> 1) * 64, wn = (wave & 1) * 64;

  const unsigned short* A = xbf + (long)rt * 128 * 768;
  const unsigned short* B = wqkvT + (long)ct * 128 * 768;
  gemm_core_nt<128, 128>(A, 768, B, B, 128, 768, 768, acc, As, Bs);

  const int b = rt >> 5;
  const int nbase = (rt & 31) * 128;
  if (ct < 6) {  // q columns -> [bh][n][d]
#pragma unroll
    for (int i = 0; i < 4; i++)
#pragma unroll
      for (int j = 0; j < 4; j++)
#pragma unroll
        for (int r = 0; r < 4; r++) {
          int col = ct * 128 + wn + j * 16 + l16;
          int h = col >> 6, d = col & 63;
          int n = nbase + wm + i * 16 + quad * 4 + r;
          q[((long)(b * 12 + h) * 4096 + n) * 64 + d] = f2bf(acc[i][j][r]);
        }
  } else {  // v columns: LDS transpose -> vT[bh][d][n]
    for (int hh = 0; hh < 2; hh++) {
      __syncthreads();
      if ((wave >> 1) == hh) {
#pragma unroll
        for (int i = 0; i < 4; i++)
#pragma unroll
          for (int j = 0; j < 4; j++)
#pragma unroll
            for (int r = 0; r < 4; r++)
              pool[(i * 16 + quad * 4 + r) * 134 + wn + j * 16 + l16] = f2bf(acc[i][j][r]);
      }
      __syncthreads();
#pragma unroll
      for (int c = 0; c < 4; c++) {
        int chunk = tid + c * 256;
        int col = chunk >> 3, nj = (chunk & 7) * 8;
        unsigned short o[8];
#pragma unroll
        for (int e = 0; e < 8; e++) o[e] = pool[(nj + e) * 134 + col];
        int vcol = ct * 128 - 768 + col;
        int h = vcol >> 6, d = vcol & 63;
        long n = nbase + hh * 64 + nj;
        *(uint4*)&vT[((long)(b * 12 + h) * 64 + d) * 4096 + n] = *(uint4*)o;
      }
    }
  }
}

// ---------------- K3: rf GEMM, full-tile staged, halfnorm folded ----------------
__global__ __launch_bounds__(256) void k_gemm_rf(const unsigned short* __restrict__ q,
                                                 const unsigned short* __restrict__ rmT,
                                                 unsigned short* __restrict__ qnT,
                                                 float* __restrict__ colss) {
  __shared__ __align__(16) unsigned short smem[16384];  // A panels | B panels; pool reuses
  __shared__ float hnp[256];
  __shared__ float css[128];
  unsigned short* Asm = smem;          // 2 panels of 128x32
  unsigned short* Bsm = smem + 8192;   // 2 panels of 128x32
  unsigned short* pool = smem;         // 64x134 transpose buffer (reuses A/B)
  f32x4 acc[4][4];
  const int nt = blockIdx.x, bh = blockIdx.y, h = bh % 12;
  const int tid = threadIdx.x, lane = tid & 63, wave = tid >> 6;
  const int l16 = lane & 15, quad = lane >> 4;
  const int wm = (wave >> 1) * 64, wn = (wave & 1) * 64;
  const int fsw = (l16 >> 1) & 3;
  const unsigned short* Aq = q + ((long)bh * 4096 + nt * 128) * 64;
  const unsigned short* Brm = rmT + (long)h * 8192;

#pragma unroll
  for (int c = 0; c < 4; c++) {  // stage full 128x64 A and B (panelized BK=32, swizzled)
    int chunk = c * 256 + tid;
    int row = chunk >> 3, ko8 = chunk & 7;
    int kc = ko8 >> 2;
    int c2s = (ko8 & 3) ^ ((row >> 1) & 3);
    *(uint4*)(Asm + kc * 4096 + row * 32 + c2s * 8) = *(const uint4*)(Aq + (long)row * 64 + ko8 * 8);
    *(uint4*)(Bsm + kc * 4096 + row * 32 + c2s * 8) = *(const uint4*)(Brm + (long)row * 64 + ko8 * 8);
  }
  for (int i = tid; i < 128; i += 256) css[i] = 0.f;
  __syncthreads();
  {  // halfnorm partials from staged q tile (sum is swizzle-invariant)
    const unsigned short* ap = Asm + (tid & 1) * 4096 + (tid >> 1) * 32;
    float ssum = 0.f;
#pragma unroll
    for (int e = 0; e < 32; e++) { float f = bf2f(ap[e]); ssum += f * f; }
    hnp[tid] = ssum;
  }
#pragma unroll
  for (int i = 0; i < 4; i++)
#pragma unroll
    for (int j = 0; j < 4; j++)
#pragma unroll
      for (int r = 0; r < 4; r++) acc[i][j][r] = 0.f;
#pragma unroll
  for (int kc = 0; kc < 2; kc++) {
    bf16x8 af[4], bfr[4];
#pragma unroll
    for (int i = 0; i < 4; i++)
      af[i] = *(const bf16x8*)(Asm + kc * 4096 + (wm + i * 16 + l16) * 32 + ((quad ^ fsw) * 8));
#pragma unroll
    for (int j = 0; j < 4; j++)
      bfr[j] = *(const bf16x8*)(Bsm + kc * 4096 + (wn + j * 16 + l16) * 32 + ((quad ^ fsw) * 8));
#pragma unroll
    for (int i = 0; i < 4; i++)
#pragma unroll
      for (int j = 0; j < 4; j++)
        acc[i][j] = __builtin_amdgcn_mfma_f32_16x16x32_bf16(af[i], bfr[j], acc[i][j], 0, 0, 0);
  }
  __syncthreads();  // hnp ready; MFMA reads of smem done (pool will reuse)
  float hnv[4][4];
#pragma unroll
  for (int i = 0; i < 4; i++)
#pragma unroll
    for (int r = 0; r < 4; r++) {
      int row = wm + i * 16 + quad * 4 + r;
      hnv[i][r] = 0.0625f * (hnp[2 * row] + hnp[2 * row + 1]);  // 0.5*scale*||q||^2
    }
#pragma unroll
  for (int j = 0; j < 4; j++) {
    int col = wn + j * 16 + l16;
    float cp = 0.f;
#pragma unroll
    for (int i = 0; i < 4; i++)
#pragma unroll
      for (int r = 0; r < 4; r++) {
        float v = __expf(acc[i][j][r] - hnv[i][r]) * 0.08838834764831845f;  // /sqrt(128)
        acc[i][j][r] = v;
        cp += v * v;
      }
    atomicAdd(&css[col], cp);
  }
  __syncthreads();
  for (int i = tid; i < 128; i += 256) atomicAdd(&colss[bh * 128 + i], css[i]);
  // transposed write rf -> qnT[bh][m][n]
  for (int hh = 0; hh < 2; hh++) {
    __syncthreads();
    if ((wave >> 1) == hh) {
#pragma unroll
      for (int i = 0; i < 4; i++)
#pragma unroll
        for (int j = 0; j < 4; j++)
#pragma unroll
          for (int r = 0; r < 4; r++)
            pool[(i * 16 + quad * 4 + r) * 134 + wn + j * 16 + l16] = f2bf(acc[i][j][r]);
    }
    __syncthreads();
#pragma unroll
    for (int c = 0; c < 4; c++) {
      int chunk = tid + c * 256;
      int m = chunk >> 3, nj = (chunk & 7) * 8;
      unsigned short o[8];
#pragma unroll
      for (int e = 0; e < 8; e++) o[e] = pool[(nj + e) * 134 + m];
      *(uint4*)&qnT[((long)bh * 128 + m) * 4096 + nt * 128 + hh * 64 + nj] = *(uint4*)o;
    }
  }
}

// ---------------- K5: kk|kv NT GEMM, rn-scaled, bf16 K-split partials ----------------
__global__ __launch_bounds__(256) void k_gemm_kkkv(const unsigned short* __restrict__ qnT,
                                                   const unsigned short* __restrict__ vT,
                                                   const float* __restrict__ colss,
                                                   unsigned short* __restrict__ kkp) {
  __shared__ __align__(16) unsigned short As[128 * 32], Bs[192 * 32];
  f32x4 acc[4][6];
  const int ks = blockIdx.x, bh = blockIdx.y;
  const unsigned short* A = qnT + (long)bh * 128 * 4096 + ks * 512;
  const unsigned short* B1 = vT + (long)bh * 64 * 4096 + ks * 512;
  gemm_core_nt<128, 192>(A, 4096, A, B1, 128, 4096, 512, acc, As, Bs);
  const int lane = threadIdx.x & 63, wave = threadIdx.x >> 6;
  const int l16 = lane & 15, quad = lane >> 4;
  const int wm = (wave >> 1) * 64, wn = (wave & 1) * 96;
  unsigned short* dst = kkp + ((long)ks * 96 + bh) * 24576;
  float rnr[4][4];
#pragma unroll
  for (int i = 0; i < 4; i++)
#pragma unroll
    for (int r = 0; r < 4; r++)
      rnr[i][r] = rn_of(colss[bh * 128 + wm + i * 16 + quad * 4 + r]);
#pragma unroll
  for (int j = 0; j < 6; j++) {
    int col = wn + j * 16 + l16;
    float rnc = (col < 128) ? rn_of(colss[bh * 128 + col]) : 1.f;
#pragma unroll
    for (int i = 0; i < 4; i++)
#pragma unroll
      for (int r = 0; r < 4; r++) {
        int row = wm + i * 16 + quad * 4 + r;
        dst[row * 192 + col] = f2bf(acc[i][j][r] * rnr[i][r] * rnc);
      }
  }
}

// ---------------- K6: ISTA via MFMA; reduces bf16 partials in fp32 ----------------
__global__ __launch_bounds__(256) void k_ista(const unsigned short* __restrict__ kkp,
                                              const float* __restrict__ colss,
                                              unsigned short* __restrict__ sT) {
  __shared__ __align__(16) unsigned short kks[128 * 144];  // kk bf16
  __shared__ __align__(16) unsigned short ssT[64 * 144];   // s^T bf16 [d][p]
  __shared__ float kvs[128 * 64];                          // kv fp32
  __shared__ float red[128];
  __shared__ float rns[128];
  const int tid = threadIdx.x, lane = tid & 63, wave = tid >> 6;
  const int l16 = lane & 15, quad = lane >> 4;
  const int wm = (wave >> 1) * 64, wn = (wave & 1) * 32;
  const int bh = blockIdx.x;
  const unsigned short* base = kkp + (long)bh * 24576;
  for (int idx = tid; idx < 3072; idx += 256) {  // 128 rows x 24 chunks of 8
    int m = idx / 24, c8 = idx % 24;
    float f[8] = {0.f, 0.f, 0.f, 0.f, 0.f, 0.f, 0.f, 0.f};
#pragma unroll
    for (int ks = 0; ks < 8; ks++) {
      union { uint4 u; unsigned short s[8]; } u;
      u.u = *(const uint4*)(base + (long)ks * 2359296 + m * 192 + c8 * 8);
#pragma unroll
      for (int e = 0; e < 8; e++) f[e] += bf2f(u.s[e]);
    }
    if (c8 < 16) {
#pragma unroll
      for (int e = 0; e < 8; e++) kks[m * 144 + c8 * 8 + e] = f2bf(f[e]);
    } else {
#pragma unroll
      for (int e = 0; e < 8; e++) kvs[m * 64 + (c8 - 16) * 8 + e] = f[e];
    }
  }
  __syncthreads();
  float kv[4][2][4];
#pragma unroll
  for (int i = 0; i < 4; i++)
#pragma unroll
    for (int j = 0; j < 2; j++)
#pragma unroll
      for (int r = 0; r < 4; r++) {
        int m = wm + i * 16 + quad * 4 + r, d = wn + j * 16 + l16;
        kv[i][j][r] = kvs[m * 64 + d];
      }
  if (tid < 128) {  // row L1 norms + rn
    float rs = 0.f;
    const unsigned short* rp = kks + tid * 144;
    for (int p = 0; p < 128; p++) rs += fabsf(bf2f(rp[p]));
    red[tid] = rs;
    rns[tid] = rn_of(colss[bh * 128 + tid]);
  }
  __syncthreads();
  for (int o = 64; o > 0; o >>= 1) {
    if (tid < o) red[tid] = fmaxf(red[tid], red[tid + o]);
    __syncthreads();
  }
  const float L = red[0] + 1.f;
  const float invL = 1.f / L;
  const float lamL = 0.3f * invL;
  float sreg[4][2][4];
#pragma unroll
  for (int i = 0; i < 4; i++)
#pragma unroll
    for (int j = 0; j < 2; j++)
#pragma unroll
      for (int r = 0; r < 4; r++) {
        float z = kv[i][j][r];
        float az = fabsf(z) - 0.3f;
        float s = az > 0.f ? copysignf(az, z) : 0.f;
        sreg[i][j][r] = s;
        ssT[(wn + j * 16 + l16) * 144 + wm + i * 16 + quad * 4 + r] = f2bf(s);
      }
  for (int step = 0; step < 5; step++) {
    __syncthreads();
    f32x4 acc[4][2];
#pragma unroll
    for (int i = 0; i < 4; i++)
#pragma unroll
      for (int j = 0; j < 2; j++)
#pragma unroll
        for (int r = 0; r < 4; r++) acc[i][j][r] = 0.f;
#pragma unroll
    for (int kc = 0; kc < 4; kc++) {
      bf16x8 af[4], bfj[2];
#pragma unroll
      for (int i = 0; i < 4; i++)
        af[i] = *(const bf16x8*)(kks + (wm + i * 16 + l16) * 144 + kc * 32 + quad * 8);
#pragma unroll
      for (int j = 0; j < 2; j++)
        bfj[j] = *(const bf16x8*)(ssT + (wn + j * 16 + l16) * 144 + kc * 32 + quad * 8);
#pragma unroll
      for (int i = 0; i < 4; i++)
#pragma unroll
        for (int j = 0; j < 2; j++)
          acc[i][j] = __builtin_amdgcn_mfma_f32_16x16x32_bf16(af[i], bfj[j], acc[i][j], 0, 0, 0);
    }
    __syncthreads();
#pragma unroll
    for (int i = 0; i < 4; i++)
#pragma unroll
      for (int j = 0; j < 2; j++)
#pragma unroll
        for (int r = 0; r < 4; r++) {
          float z = sreg[i][j][r] - (acc[i][j][r] - kv[i][j][r]) * invL;
          float az = fabsf(z) - lamL;
          float s = az > 0.f ? copysignf(az, z) : 0.f;
          sreg[i][j][r] = s;
          ssT[(wn + j * 16 + l16) * 144 + wm + i * 16 + quad * 4 + r] = f2bf(s);
        }
  }
#pragma unroll
  for (int i = 0; i < 4; i++)
#pragma unroll
    for (int j = 0; j < 2; j++)
#pragma unroll
      for (int r = 0; r < 4; r++) {
        int m = wm + i * 16 + quad * 4 + r, d = wn + j * 16 + l16;
        sT[(long)bh * 8192 + d * 128 + m] = f2bf(sreg[i][j][r] * rns[m]);  // fold rn[m]
      }
}

// ---------------- K7: attn = qn @ s (TN over qnT, gather-staged) ----------------
__global__ __launch_bounds__(256) void k_gemm_attn(const unsigned short* __restrict__ qnT,
                                                   const unsigned short* __restrict__ sT,
                                                   unsigned short* __restrict__ attn) {
  __shared__ __align__(16) unsigned short As2[32 * 128];  // [k][n]
  __shared__ __align__(16) unsigned short Bs[64 * 32];
  f32x4 acc[4][2];
  const int nt = blockIdx.x, bh = blockIdx.y;
  const int b = bh / 12, h = bh % 12;
  const int tid = threadIdx.x, lane = tid & 63, wave = tid >> 6;
  const int l16 = lane & 15, quad = lane >> 4;
  const int wm = (wave >> 1) * 64, wn = (wave & 1) * 32;
  const int fsw = (l16 >> 1) & 3;
#pragma unroll
  for (int i = 0; i < 4; i++)
#pragma unroll
    for (int j = 0; j < 2; j++)
#pragma unroll
      for (int r = 0; r < 4; r++) acc[i][j][r] = 0.f;
  for (int k0 = 0; k0 < 128; k0 += 32) {
    __syncthreads();
#pragma unroll
    for (int c = 0; c < 2; c++) {
      int chunk = tid + c * 256;
      int kr = chunk >> 4, n0 = (chunk & 15) * 8;
      const unsigned short* gp = qnT + ((long)bh * 128 + k0 + kr) * 4096 + nt * 128 + n0;
      GLD16(gp, As2 + (c * 256 + wave * 64) * 8);
    }
    {
      int dd = tid >> 2;
      int ko = (((tid & 3) ^ ((dd >> 1) & 3)) * 8);  // swizzled
      const unsigned short* gp = sT + ((long)bh * 64 + dd) * 128 + k0 + ko;
      GLD16(gp, Bs + wave * 512);
    }
    __syncthreads();
    bf16x8 af[4], bfr[2];
#pragma unroll
    for (int i = 0; i < 4; i++) {
      union { bf16x8 v; unsigned short s[8]; } u;
#pragma unroll
      for (int e = 0; e < 8; e++) u.s[e] = As2[(quad * 8 + e) * 128 + wm + i * 16 + l16];
      af[i] = u.v;
    }
#pragma unroll
    for (int j = 0; j < 2; j++)
      bfr[j] = *(const bf16x8*)&Bs[(wn + j * 16 + l16) * 32 + ((quad ^ fsw) * 8)];
#pragma unroll
    for (int i = 0; i < 4; i++)
#pragma unroll
      for (int j = 0; j < 2; j++)
        acc[i][j] = __builtin_amdgcn_mfma_f32_16x16x32_bf16(af[i], bfr[j], acc[i][j], 0, 0, 0);
  }
#pragma unroll
  for (int i = 0; i < 4; i++)
#pragma unroll
    for (int j = 0; j < 2; j++)
#pragma unroll
      for (int r = 0; r < 4; r++) {
        int n = nt * 128 + wm + i * 16 + quad * 4 + r;
        int dd = wn + j * 16 + l16;
        attn[((long)b * 4096 + n) * 768 + h * 64 + dd] = f2bf(acc[i][j][r]);
      }
}

// ---------------- K8: out = attn @ Wproj + bias, XCD-swizzled ----------------
__global__ __launch_bounds__(256) void k_gemm_proj(const unsigned short* __restrict__ attn,
                                                   const unsigned short* __restrict__ wprojT,
                                                   const float* __restrict__ bias,
                                                   float* __restrict__ out) {
  __shared__ __align__(16) unsigned short As[128 * 32], Bs[128 * 32];
  f32x4 acc[4][4];
  const int Lb = blockIdx.x;
  const int xcd = Lb & 7, slot = Lb >> 3;
  const int rt = xcd * 32 + slot / 6;
  const int ct = slot % 6;
  const unsigned short* A = attn + (long)rt * 128 * 768;
  const unsigned short* B = wprojT + (long)ct * 128 * 768;
  gemm_core_nt<128, 128>(A, 768, B, B, 128, 768, 768, acc, As, Bs);
  const int lane = threadIdx.x & 63, wave = threadIdx.x >> 6;
  const int l16 = lane & 15, quad = lane >> 4;
  const int wm = (wave >> 1) * 64, wn = (wave & 1) * 64;
  long row0 = (long)rt * 128, col0 = (long)ct * 128;
#pragma unroll
  for (int i = 0; i < 4; i++)
#pragma unroll
    for (int j = 0; j < 4; j++) {
      int col = (int)col0 + wn + j * 16 + l16;
      float bv = bias[col];
#pragma unroll
      for (int r = 0; r < 4; r++) {
        long row = row0 + wm + i * 16 + quad * 4 + r;
        out[row * 768 + col] = acc[i][j][r] + bv;
      }
    }
}

extern "C" void kernel_launch(void* const* d_in, const int* in_sizes, int n_in,
                              void* d_out, int out_size, void* d_ws, size_t ws_size,
                              hipStream_t stream) {
  const float* x = (const float*)d_in[0];
  const float* Wqkv = (const float*)d_in[1];
  const float* Wproj = (const float*)d_in[2];
  const float* bproj = (const float*)d_in[3];
  const float* rm = (const float*)d_in[4];
  float* out = (float*)d_out;

  size_t o = 0;
  char* wsb = (char*)d_ws;
  auto take = [&](size_t b) { char* p = wsb + o; o += b; return p; };
  unsigned short* wqkvT = (unsigned short*)take(2359296);
  unsigned short* wprojT = (unsigned short*)take(1179648);
  unsigned short* rmT = (unsigned short*)take(196608);
  unsigned short* q = (unsigned short*)take(50331648);    // reused: kkp (37.7MB), then attn
  unsigned short* vT = (unsigned short*)take(50331648);
  float* colss = (float*)take(49152);
  unsigned short* sT = (unsigned short*)take(1572864);
  // total = 106,020,864 B (~101 MB, < proven 110 MB)
  if (ws_size < o) return;

  unsigned short* xbf = (unsigned short*)d_out;  // 48 MB; dead before qnT claims d_out
  unsigned short* qnT = (unsigned short*)d_out;  // 100.66 MB == out bytes; dead before K8
  unsigned short* kkp = q;                       // alias: q dead after rf
  unsigned short* attnbf = q;                    // alias: kkp dead after ista

  hipMemsetAsync(colss, 0, 49152, stream);

  k_convert_bf16<<<24576, 256, 0, stream>>>(x, xbf, 6291456L);
  k_transpose_tiled<<<dim3(48, 24, 1), 256, 0, stream>>>(Wqkv, wqkvT, 768, 1536, 1.0f);
  k_transpose_tiled<<<dim3(24, 24, 1), 256, 0, stream>>>(Wproj, wprojT, 768, 768, 1.0f);
  // fold qs = q * scale^0.5 into rand_matrix (scale^0.5 = 8^-0.5)
  k_transpose_tiled<<<dim3(4, 2, 12), 256, 0, stream>>>(rm, rmT, 64, 128, 0.3535533905932738f);
  k_gemm_qkv<<<3072, 256, 0, stream>>>(xbf, wqkvT, q, vT);
  k_gemm_rf<<<dim3(32, 96), 256, 0, stream>>>(q, rmT, qnT, colss);
  k_gemm_kkkv<<<dim3(8, 96), 256, 0, stream>>>(qnT, vT, colss, kkp);
  k_ista<<<96, 256, 0, stream>>>(kkp, colss, sT);
  k_gemm_attn<<<dim3(32, 96), 256, 0, stream>>>(qnT, sT, attnbf);
  k_gemm_proj<<<1536, 256, 0, stream>>>(attnbf, wprojT, bproj, out);
}